// Round 4
// baseline (404.082 us; speedup 1.0000x reference)
//
#include <hip/hip_runtime.h>

typedef unsigned short u16;
typedef __attribute__((ext_vector_type(8))) short short8;
typedef __attribute__((ext_vector_type(4))) float floatx4;
typedef __attribute__((ext_vector_type(4))) unsigned short ushortx4;

#define DEV static __device__ __forceinline__

DEV float bf2f(u16 u) { union { unsigned u; float f; } v; v.u = ((unsigned)u) << 16; return v.f; }
DEV u16 f2bf(float f) {
  union { float f; unsigned u; } v; v.f = f;
  return (u16)((v.u + 0x7FFFu + ((v.u >> 16) & 1u)) >> 16);  // RNE; finite inputs
}

// async global->LDS, 16B/lane, LDS dest = wave-uniform base + lane*16 (m97-proven form)
#define GLDS(g, l) __builtin_amdgcn_global_load_lds( \
    (const __attribute__((address_space(1))) void*)(g), \
    (__attribute__((address_space(3))) void*)(l), 16, 0, 0)

// ---------------- fp32 -> bf16 conversion of all 11 inputs ----------------
struct CvtArg {
  const float* src[11];
  u16* dst[11];
  int cum[12];  // cumulative element offsets (all segment sizes are multiples of 4)
};

__global__ void convert(CvtArg a) {
  const long base = ((long)blockIdx.x * 256 + threadIdx.x) * 4;
  if (base >= a.cum[11]) return;
  int s = 0;
  while (s < 10 && base >= a.cum[s + 1]) ++s;
  const long off = base - a.cum[s];
  const float* sp = a.src[s] + off;
  ushortx4 u;
#pragma unroll
  for (int r = 0; r < 4; ++r) u[r] = f2bf(sp[r]);
  *(ushortx4*)(a.dst[s] + off) = u;
}

// ---------------- projection GEMMs (m97 structure) ----------------
struct GemmArg {
  const u16* x;    // [4096][1024] bf16
  const u16* w;    // [1024][1024] bf16 (torch W: y = x @ W.T + b -> NT gemm)
  const u16* bias; // [1024] bf16
  u16* dst;        // mode 3: reinterpreted as float*
  int mode;        // 0=Q (BHSD, *0.125)  1=K (BHSD)  2=V^T (BHDS)  3=fp32 [M][N]
};

__global__ __launch_bounds__(256, 2) void gemm_nt(GemmArg g0, GemmArg g1, GemmArg g2) {
  GemmArg g = (blockIdx.z == 0) ? g0 : ((blockIdx.z == 1) ? g1 : g2);
  __shared__ u16 As[128 * 32];
  __shared__ u16 Bs[128 * 32];
  const int tid = threadIdx.x, w = tid >> 6, l = tid & 63;
  const int l15 = l & 15, quad = l >> 4;
  const int bm = blockIdx.x, bn = blockIdx.y;
  const int wm = w >> 1, wn = w & 1;

  floatx4 acc[4][4];
#pragma unroll
  for (int i = 0; i < 4; ++i)
#pragma unroll
    for (int j = 0; j < 4; ++j) acc[i][j] = (floatx4){0.f, 0.f, 0.f, 0.f};

  const u16* xb = g.x + (long)(bm * 128 + w * 16 + (l >> 2)) * 1024 + (l & 3) * 8;
  const u16* wb = g.w + (long)(bn * 128 + w * 16 + (l >> 2)) * 1024 + (l & 3) * 8;
  u16* asb = &As[(w * 16) * 32];
  u16* bsb = &Bs[(w * 16) * 32];

  for (int kt = 0; kt < 32; ++kt) {
    const int k0 = kt * 32;
    __syncthreads();
#pragma unroll
    for (int p = 0; p < 2; ++p) {
      GLDS(xb + (long)p * 64 * 1024 + k0, asb + p * 64 * 32);
      GLDS(wb + (long)p * 64 * 1024 + k0, bsb + p * 64 * 32);
    }
    __syncthreads();
    short8 af[4], bfr[4];
#pragma unroll
    for (int mi = 0; mi < 4; ++mi)
      af[mi] = *(const short8*)&As[(wm * 64 + mi * 16 + l15) * 32 + quad * 8];
#pragma unroll
    for (int ni = 0; ni < 4; ++ni)
      bfr[ni] = *(const short8*)&Bs[(wn * 64 + ni * 16 + l15) * 32 + quad * 8];
#pragma unroll
    for (int mi = 0; mi < 4; ++mi)
#pragma unroll
      for (int ni = 0; ni < 4; ++ni)
        acc[mi][ni] = __builtin_amdgcn_mfma_f32_16x16x32_bf16(af[mi], bfr[ni], acc[mi][ni], 0, 0, 0);
  }

  float bv[4];
#pragma unroll
  for (int ni = 0; ni < 4; ++ni) bv[ni] = bf2f(g.bias[bn * 128 + wn * 64 + ni * 16 + l15]);

  // C/D layout: col = lane&15, row = quad*4 + reg  [m89/m91]
#pragma unroll
  for (int mi = 0; mi < 4; ++mi) {
    const int mbase = bm * 128 + wm * 64 + mi * 16 + quad * 4;
#pragma unroll
    for (int ni = 0; ni < 4; ++ni) {
      const int n = bn * 128 + wn * 64 + ni * 16 + l15;
      if (g.mode == 2) {  // V^T [B,H,64,2048]
        const int b = mbase >> 11, s = mbase & 2047;
        const int h = n >> 6, d = n & 63;
        ushortx4 u;
#pragma unroll
        for (int r = 0; r < 4; ++r) u[r] = f2bf(acc[mi][ni][r] + bv[ni]);
        *(ushortx4*)&g.dst[((long)(b * 16 + h) * 64 + d) * 2048 + s] = u;
      } else if (g.mode == 3) {  // fp32 [4096][1024] -> d_out
        float* df = (float*)g.dst;
#pragma unroll
        for (int r = 0; r < 4; ++r)
          df[(long)(mbase + r) * 1024 + n] = acc[mi][ni][r] + bv[ni];
      } else {  // Q/K -> [B,H,2048,64]; Q folds 1/sqrt(64)
        const float sc = (g.mode == 0) ? 0.125f : 1.0f;
        const int h = n >> 6, d = n & 63;
#pragma unroll
        for (int r = 0; r < 4; ++r) {
          const int m = mbase + r, b = m >> 11, s = m & 2047;
          g.dst[((long)(b * 16 + h) * 2048 + s) * 64 + d] = f2bf((acc[mi][ni][r] + bv[ni]) * sc);
        }
      }
    }
  }
}

// ---------------- attention (bisect-simple, m97-pattern fragments only) ----------------
__global__ __launch_bounds__(256, 4) void attn_simple(const u16* __restrict__ Q,
                                                      const u16* __restrict__ K,
                                                      const u16* __restrict__ V,
                                                      u16* __restrict__ X) {
  __shared__ float Sw[4][16][32];  // per-wave exp'd scores [q_local][kv_local]
  __shared__ float denW[4][16];
  const int tid = threadIdx.x, w = tid >> 6, l = tid & 63;
  const int l15 = l & 15, quad = l >> 4;
  const int q0 = blockIdx.x * 64, bh = blockIdx.y;
  const u16* qp = Q + (long)bh * 2048 * 64;  // [2048][64], pre-scaled by 0.125
  const u16* kp = K + (long)bh * 2048 * 64;  // [2048][64]
  const u16* vp = V + (long)bh * 2048 * 64;  // [64][2048] (V^T)

  short8 qf[2];
#pragma unroll
  for (int kc = 0; kc < 2; ++kc)
    qf[kc] = *(const short8*)(qp + (long)(q0 + w * 16 + l15) * 64 + kc * 32 + quad * 8);

  floatx4 o[4];
#pragma unroll
  for (int nd = 0; nd < 4; ++nd) o[nd] = (floatx4){0.f, 0.f, 0.f, 0.f};
  float den = 0.f;

  for (int kv0 = 0; kv0 < 2048; kv0 += 32) {
#pragma unroll
    for (int kvh = 0; kvh < 2; ++kvh) {
      const u16* krow = kp + (long)(kv0 + kvh * 16 + l15) * 64;
      short8 a0 = *(const short8*)(krow + quad * 8);
      short8 a1 = *(const short8*)(krow + 32 + quad * 8);
      floatx4 st = (floatx4){0.f, 0.f, 0.f, 0.f};
      st = __builtin_amdgcn_mfma_f32_16x16x32_bf16(a0, qf[0], st, 0, 0, 0);
      st = __builtin_amdgcn_mfma_f32_16x16x32_bf16(a1, qf[1], st, 0, 0, 0);
#pragma unroll
      for (int r = 0; r < 4; ++r) {
        const float e = __expf(fminf(fmaxf(st[r], -30.f), 30.f));
        den += e;
        Sw[w][l15][kvh * 16 + quad * 4 + r] = e;
      }
    }
    short8 ap;
#pragma unroll
    for (int j = 0; j < 8; ++j) ap[j] = (short)f2bf(Sw[w][l15][quad * 8 + j]);
#pragma unroll
    for (int nd = 0; nd < 4; ++nd) {
      short8 bv = *(const short8*)(vp + (long)(nd * 16 + l15) * 2048 + kv0 + quad * 8);
      o[nd] = __builtin_amdgcn_mfma_f32_16x16x32_bf16(ap, bv, o[nd], 0, 0, 0);
    }
  }

  float d = den;
  d += __shfl_xor(d, 16);
  d += __shfl_xor(d, 32);
  if (l < 16) denW[w][l] = 1.0f / d;

  const int b = bh >> 4, h = bh & 15;
#pragma unroll
  for (int r = 0; r < 4; ++r) {
    const float rcp = denW[w][quad * 4 + r];
    const int s = q0 + w * 16 + quad * 4 + r;
    u16* xrow = X + ((long)(b * 2048 + s)) * 1024 + h * 64;
#pragma unroll
    for (int nd = 0; nd < 4; ++nd)
      xrow[nd * 16 + l15] = f2bf(o[nd][r] * rcp);
  }
}

extern "C" void kernel_launch(void* const* d_in, const int* in_sizes, int n_in,
                              void* d_out, int out_size, void* d_ws, size_t ws_size,
                              hipStream_t stream) {
  u16* ws = (u16*)d_ws;
  const size_t M1 = 1048576, M4 = 4194304;
  // bf16 copies of the fp32 inputs
  u16* NQ  = ws;                    // [4M] (reused as Xb after QKV gemm)
  u16* NK  = ws + M4;
  u16* NV  = ws + 2 * M4;
  u16* NWQ = ws + 3 * M4;
  u16* NWK = ws + 3 * M4 + M1;
  u16* NWV = ws + 3 * M4 + 2 * M1;
  u16* NWO = ws + 3 * M4 + 3 * M1;
  u16* NBQ = ws + 3 * M4 + 4 * M1;
  u16* NBK = NBQ + 1024;
  u16* NBV = NBQ + 2048;
  u16* NBO = NBQ + 3072;
  // intermediates
  u16* Qb = ws + 16 * M1 + 8192;    // [32][2048][64], q*0.125
  u16* Kb = Qb + M4;                // [32][2048][64]
  u16* Vb = Qb + 2 * M4;            // [32][64][2048] (V^T)
  u16* Xb = NQ;                     // [4096][1024]  (total ws use: ~56 MB)

  CvtArg ca;
  u16* dsts[11] = {NQ, NK, NV, NWQ, NBQ, NWK, NBK, NWV, NBV, NWO, NBO};
  int sizes[11] = {(int)M4, (int)M4, (int)M4, (int)M1, 1024, (int)M1, 1024, (int)M1, 1024, (int)M1, 1024};
  int c = 0;
  for (int i = 0; i < 11; ++i) {
    ca.src[i] = (const float*)d_in[i];
    ca.dst[i] = dsts[i];
    ca.cum[i] = c;
    c += sizes[i];
  }
  ca.cum[11] = c;  // 16,781,312
  convert<<<(c / 4 + 255) / 256, 256, 0, stream>>>(ca);

  GemmArg gq{NQ, NWQ, NBQ, Qb, 0};
  GemmArg gk{NK, NWK, NBK, Kb, 1};
  GemmArg gv{NV, NWV, NBV, Vb, 2};
  gemm_nt<<<dim3(32, 8, 3), 256, 0, stream>>>(gq, gk, gv);

  attn_simple<<<dim3(32, 32), 256, 0, stream>>>(Qb, Kb, Vb, Xb);

  GemmArg go{Xb, NWO, NBO, (u16*)d_out, 3};
  gemm_nt<<<dim3(32, 8, 1), 256, 0, stream>>>(go, go, go);
}

// Round 5
// 247.776 us; speedup vs baseline: 1.6308x; 1.6308x over previous
//
#include <hip/hip_runtime.h>

typedef unsigned short u16;
typedef __attribute__((ext_vector_type(8))) short short8;
typedef __attribute__((ext_vector_type(4))) float floatx4;
typedef __attribute__((ext_vector_type(4))) unsigned short ushortx4;

#define DEV static __device__ __forceinline__

DEV float bf2f(u16 u) { union { unsigned u; float f; } v; v.u = ((unsigned)u) << 16; return v.f; }
DEV u16 f2bf(float f) {
  union { float f; unsigned u; } v; v.f = f;
  return (u16)((v.u + 0x7FFFu + ((v.u >> 16) & 1u)) >> 16);  // RNE; finite inputs
}

// async global->LDS, 16B/lane, LDS dest = wave-uniform base + lane*16 (m97-proven form)
#define GLDS(g, l) __builtin_amdgcn_global_load_lds( \
    (const __attribute__((address_space(1))) void*)(g), \
    (__attribute__((address_space(3))) void*)(l), 16, 0, 0)

// ---------------- fp32 -> bf16 conversion of all 11 inputs ----------------
struct CvtArg {
  const float* src[11];
  u16* dst[11];
  int cum[12];
};

__global__ void convert(CvtArg a) {
  const long base = ((long)blockIdx.x * 256 + threadIdx.x) * 4;
  if (base >= a.cum[11]) return;
  int s = 0;
  while (s < 10 && base >= a.cum[s + 1]) ++s;
  const long off = base - a.cum[s];
  const float* sp = a.src[s] + off;
  ushortx4 u;
#pragma unroll
  for (int r = 0; r < 4; ++r) u[r] = f2bf(sp[r]);
  *(ushortx4*)(a.dst[s] + off) = u;
}

// ---------------- projection GEMMs (m97 structure; verbatim from passing R4) ----------------
struct GemmArg {
  const u16* x;    // [4096][1024] bf16
  const u16* w;    // [1024][1024] bf16 (torch: y = x @ W.T + b -> NT gemm)
  const u16* bias; // [1024] bf16
  u16* dst;        // mode 3: reinterpreted as float*
  int mode;        // 0=Q (BHSD, *0.125)  1=K (BHSD)  2=V^T (BHDS)  3=fp32 [M][N]
};

__global__ __launch_bounds__(256, 2) void gemm_nt(GemmArg g0, GemmArg g1, GemmArg g2) {
  GemmArg g = (blockIdx.z == 0) ? g0 : ((blockIdx.z == 1) ? g1 : g2);
  __shared__ u16 As[128 * 32];
  __shared__ u16 Bs[128 * 32];
  const int tid = threadIdx.x, w = tid >> 6, l = tid & 63;
  const int l15 = l & 15, quad = l >> 4;
  const int bm = blockIdx.x, bn = blockIdx.y;
  const int wm = w >> 1, wn = w & 1;

  floatx4 acc[4][4];
#pragma unroll
  for (int i = 0; i < 4; ++i)
#pragma unroll
    for (int j = 0; j < 4; ++j) acc[i][j] = (floatx4){0.f, 0.f, 0.f, 0.f};

  const u16* xb = g.x + (long)(bm * 128 + w * 16 + (l >> 2)) * 1024 + (l & 3) * 8;
  const u16* wb = g.w + (long)(bn * 128 + w * 16 + (l >> 2)) * 1024 + (l & 3) * 8;
  u16* asb = &As[(w * 16) * 32];
  u16* bsb = &Bs[(w * 16) * 32];

  for (int kt = 0; kt < 32; ++kt) {
    const int k0 = kt * 32;
    __syncthreads();
#pragma unroll
    for (int p = 0; p < 2; ++p) {
      GLDS(xb + (long)p * 64 * 1024 + k0, asb + p * 64 * 32);
      GLDS(wb + (long)p * 64 * 1024 + k0, bsb + p * 64 * 32);
    }
    __syncthreads();
    short8 af[4], bfr[4];
#pragma unroll
    for (int mi = 0; mi < 4; ++mi)
      af[mi] = *(const short8*)&As[(wm * 64 + mi * 16 + l15) * 32 + quad * 8];
#pragma unroll
    for (int ni = 0; ni < 4; ++ni)
      bfr[ni] = *(const short8*)&Bs[(wn * 64 + ni * 16 + l15) * 32 + quad * 8];
#pragma unroll
    for (int mi = 0; mi < 4; ++mi)
#pragma unroll
      for (int ni = 0; ni < 4; ++ni)
        acc[mi][ni] = __builtin_amdgcn_mfma_f32_16x16x32_bf16(af[mi], bfr[ni], acc[mi][ni], 0, 0, 0);
  }

  float bv[4];
#pragma unroll
  for (int ni = 0; ni < 4; ++ni) bv[ni] = bf2f(g.bias[bn * 128 + wn * 64 + ni * 16 + l15]);

  // C/D layout: col = lane&15, row = quad*4 + reg  [m89/m91]
#pragma unroll
  for (int mi = 0; mi < 4; ++mi) {
    const int mbase = bm * 128 + wm * 64 + mi * 16 + quad * 4;
#pragma unroll
    for (int ni = 0; ni < 4; ++ni) {
      const int n = bn * 128 + wn * 64 + ni * 16 + l15;
      if (g.mode == 2) {  // V^T [B,H,64,2048]
        const int b = mbase >> 11, s = mbase & 2047;
        const int h = n >> 6, d = n & 63;
        ushortx4 u;
#pragma unroll
        for (int r = 0; r < 4; ++r) u[r] = f2bf(acc[mi][ni][r] + bv[ni]);
        *(ushortx4*)&g.dst[((long)(b * 16 + h) * 64 + d) * 2048 + s] = u;
      } else if (g.mode == 3) {  // fp32 [4096][1024] -> d_out
        float* df = (float*)g.dst;
#pragma unroll
        for (int r = 0; r < 4; ++r)
          df[(long)(mbase + r) * 1024 + n] = acc[mi][ni][r] + bv[ni];
      } else {  // Q/K -> [B,H,2048,64]; Q folds 1/sqrt(64)
        const float sc = (g.mode == 0) ? 0.125f : 1.0f;
        const int h = n >> 6, d = n & 63;
#pragma unroll
        for (int r = 0; r < 4; ++r) {
          const int m = mbase + r, b = m >> 11, s = m & 2047;
          g.dst[((long)(b * 16 + h) * 2048 + s) * 64 + d] = f2bf((acc[mi][ni][r] + bv[ni]) * sc);
        }
      }
    }
  }
}

// ---------------- flash attention: Q-tile 128, kv-tile 64, LDS-staged K/V ----------------
// Same verified fragment mappings as R4's attn_simple; K/V now staged once per block
// (4-wave reuse), P kept as bf16 in padded LDS (stride 72 u16 breaks bank wrap).
__global__ __launch_bounds__(256, 3) void attn_flash(const u16* __restrict__ Q,
                                                     const u16* __restrict__ K,
                                                     const u16* __restrict__ V,
                                                     u16* __restrict__ X) {
  __shared__ u16 Ks[64 * 72];       // [kv][d], stride 72
  __shared__ u16 Vs[64 * 72];       // V^T [d][kv], stride 72
  __shared__ u16 Ps[4][32 * 72];    // per-wave P [q_local][kv], bf16, stride 72
  __shared__ float denW[4][32];
  const int tid = threadIdx.x, w = tid >> 6, l = tid & 63;
  const int l15 = l & 15, quad = l >> 4;
  const int q0 = blockIdx.x * 128, bh = blockIdx.y;
  const u16* qp = Q + (long)bh * 2048 * 64;  // [2048][64], pre-scaled by 0.125
  const u16* kp = K + (long)bh * 2048 * 64;  // [2048][64]
  const u16* vp = V + (long)bh * 2048 * 64;  // [64][2048] (V^T)

  // Q fragments (B-operand of S^T = K*Q^T): lane holds Q[q=l15][d=kc*32+quad*8+j]
  short8 qf[2][2];
#pragma unroll
  for (int nq = 0; nq < 2; ++nq)
#pragma unroll
    for (int kc = 0; kc < 2; ++kc)
      qf[nq][kc] = *(const short8*)(qp + (long)(q0 + w * 32 + nq * 16 + l15) * 64 + kc * 32 + quad * 8);

  floatx4 o[2][4];
#pragma unroll
  for (int mq = 0; mq < 2; ++mq)
#pragma unroll
    for (int nd = 0; nd < 4; ++nd) o[mq][nd] = (floatx4){0.f, 0.f, 0.f, 0.f};
  float den[2] = {0.f, 0.f};

  for (int kv0 = 0; kv0 < 2048; kv0 += 64) {
    __syncthreads();
    // stage K tile [64 kv][64 d] and V^T tile [64 d][64 kv]; 512 16B-chunks each
#pragma unroll
    for (int i = 0; i < 2; ++i) {
      const int ci = i * 256 + tid;
      const int r = ci >> 3, c8 = ci & 7;
      short8 tk = *(const short8*)(kp + (long)(kv0 + r) * 64 + c8 * 8);
      short8 tv = *(const short8*)(vp + (long)r * 2048 + kv0 + c8 * 8);
      *(short8*)&Ks[r * 72 + c8 * 8] = tk;
      *(short8*)&Vs[r * 72 + c8 * 8] = tv;
    }
    __syncthreads();

    // S^T[kv][q]: A = K rows (m=kv), B = Q^T (n=q). D: kv = mk*16+quad*4+r, q = l15.
#pragma unroll
    for (int mk = 0; mk < 4; ++mk) {
      short8 ak0 = *(const short8*)&Ks[(mk * 16 + l15) * 72 + quad * 8];
      short8 ak1 = *(const short8*)&Ks[(mk * 16 + l15) * 72 + 32 + quad * 8];
#pragma unroll
      for (int nq = 0; nq < 2; ++nq) {
        floatx4 st = (floatx4){0.f, 0.f, 0.f, 0.f};
        st = __builtin_amdgcn_mfma_f32_16x16x32_bf16(ak0, qf[nq][0], st, 0, 0, 0);
        st = __builtin_amdgcn_mfma_f32_16x16x32_bf16(ak1, qf[nq][1], st, 0, 0, 0);
#pragma unroll
        for (int r = 0; r < 4; ++r) {
          const float e = __expf(fminf(fmaxf(st[r], -30.f), 30.f));
          den[nq] += e;
          Ps[w][(nq * 16 + l15) * 72 + mk * 16 + quad * 4 + r] = f2bf(e);
        }
      }
    }

    // O += P * V: A = P[m=q][k=kv] (b128 from own-wave Ps), B = V^T (n=d).
#pragma unroll
    for (int kc = 0; kc < 2; ++kc) {
#pragma unroll
      for (int mq = 0; mq < 2; ++mq) {
        short8 ap = *(const short8*)&Ps[w][(mq * 16 + l15) * 72 + kc * 32 + quad * 8];
#pragma unroll
        for (int nd = 0; nd < 4; ++nd) {
          short8 bvf = *(const short8*)&Vs[(nd * 16 + l15) * 72 + kc * 32 + quad * 8];
          o[mq][nd] = __builtin_amdgcn_mfma_f32_16x16x32_bf16(ap, bvf, o[mq][nd], 0, 0, 0);
        }
      }
    }
  }

  // denominator: lane's den[nq] covers q = nq*16+l15 for its quad's kv subset; sum quads
#pragma unroll
  for (int nq = 0; nq < 2; ++nq) {
    float d = den[nq];
    d += __shfl_xor(d, 16);
    d += __shfl_xor(d, 32);
    if (l < 16) denW[w][nq * 16 + l] = 1.0f / d;
  }

  const int b = bh >> 4, h = bh & 15;
#pragma unroll
  for (int mq = 0; mq < 2; ++mq) {
#pragma unroll
    for (int r = 0; r < 4; ++r) {
      const float rcp = denW[w][mq * 16 + quad * 4 + r];
      const int s = q0 + w * 32 + mq * 16 + quad * 4 + r;
      u16* xrow = X + ((long)(b * 2048 + s)) * 1024 + h * 64;
#pragma unroll
      for (int nd = 0; nd < 4; ++nd)
        xrow[nd * 16 + l15] = f2bf(o[mq][nd][r] * rcp);
    }
  }
}

extern "C" void kernel_launch(void* const* d_in, const int* in_sizes, int n_in,
                              void* d_out, int out_size, void* d_ws, size_t ws_size,
                              hipStream_t stream) {
  u16* ws = (u16*)d_ws;
  const size_t M1 = 1048576, M4 = 4194304;
  u16* NQ  = ws;                    // bf16 copies of fp32 inputs (NQ reused as Xb)
  u16* NK  = ws + M4;
  u16* NV  = ws + 2 * M4;
  u16* NWQ = ws + 3 * M4;
  u16* NWK = ws + 3 * M4 + M1;
  u16* NWV = ws + 3 * M4 + 2 * M1;
  u16* NWO = ws + 3 * M4 + 3 * M1;
  u16* NBQ = ws + 3 * M4 + 4 * M1;
  u16* NBK = NBQ + 1024;
  u16* NBV = NBQ + 2048;
  u16* NBO = NBQ + 3072;
  u16* Qb = ws + 16 * M1 + 8192;    // [32][2048][64], q*0.125
  u16* Kb = Qb + M4;                // [32][2048][64]
  u16* Vb = Qb + 2 * M4;            // [32][64][2048] (V^T)
  u16* Xb = NQ;                     // [4096][1024]

  CvtArg ca;
  u16* dsts[11] = {NQ, NK, NV, NWQ, NBQ, NWK, NBK, NWV, NBV, NWO, NBO};
  int sizes[11] = {(int)M4, (int)M4, (int)M4, (int)M1, 1024, (int)M1, 1024, (int)M1, 1024, (int)M1, 1024};
  int c = 0;
  for (int i = 0; i < 11; ++i) {
    ca.src[i] = (const float*)d_in[i];
    ca.dst[i] = dsts[i];
    ca.cum[i] = c;
    c += sizes[i];
  }
  ca.cum[11] = c;
  convert<<<(c / 4 + 255) / 256, 256, 0, stream>>>(ca);

  GemmArg gq{NQ, NWQ, NBQ, Qb, 0};
  GemmArg gk{NK, NWK, NBK, Kb, 1};
  GemmArg gv{NV, NWV, NBV, Vb, 2};
  gemm_nt<<<dim3(32, 8, 3), 256, 0, stream>>>(gq, gk, gv);

  attn_flash<<<dim3(16, 32), 256, 0, stream>>>(Qb, Kb, Vb, Xb);

  GemmArg go{Xb, NWO, NBO, (u16*)d_out, 3};
  gemm_nt<<<dim3(32, 8, 1), 256, 0, stream>>>(go, go, go);
}

// Round 7
// 240.344 us; speedup vs baseline: 1.6813x; 1.0309x over previous
//
#include <hip/hip_runtime.h>

typedef unsigned short u16;
typedef unsigned int u32;
typedef __attribute__((ext_vector_type(8))) short short8;
typedef __attribute__((ext_vector_type(4))) float floatx4;
typedef __attribute__((ext_vector_type(4))) unsigned short ushortx4;
typedef __attribute__((ext_vector_type(2))) unsigned int uint2v;

#define DEV static __device__ __forceinline__

DEV float bf2f(u16 u) { union { unsigned u; float f; } v; v.u = ((unsigned)u) << 16; return v.f; }
DEV u16 f2bf(float f) {
  union { float f; unsigned u; } v; v.f = f;
  return (u16)((v.u + 0x7FFFu + ((v.u >> 16) & 1u)) >> 16);  // RNE; finite inputs
}
// pack two floats to two bf16 (round-half-up) in one v_perm
DEV u32 pkbf(float a, float b) {
  union { float f; u32 u; } x, y; x.f = a; y.f = b;
  return __builtin_amdgcn_perm(y.u + 0x8000u, x.u + 0x8000u, 0x07060302u);
}
DEV float fexp2(float x) { return __builtin_amdgcn_exp2f(x); }  // v_exp_f32

// async global->LDS, 16B/lane, LDS dest = wave-uniform base + lane*16 (m97-proven form)
#define GLDS(g, l) __builtin_amdgcn_global_load_lds( \
    (const __attribute__((address_space(1))) void*)(g), \
    (__attribute__((address_space(3))) void*)(l), 16, 0, 0)

// ---------------- fp32 -> bf16 conversion of all 11 inputs ----------------
struct CvtArg {
  const float* src[11];
  u16* dst[11];
  int cum[12];
};

__global__ void convert(CvtArg a) {
  const long base = ((long)blockIdx.x * 256 + threadIdx.x) * 4;
  if (base >= a.cum[11]) return;
  int s = 0;
  while (s < 10 && base >= a.cum[s + 1]) ++s;
  const long off = base - a.cum[s];
  const float* sp = a.src[s] + off;
  ushortx4 u;
#pragma unroll
  for (int r = 0; r < 4; ++r) u[r] = f2bf(sp[r]);
  *(ushortx4*)(a.dst[s] + off) = u;
}

// ---------------- projection GEMMs (m97 structure; verbatim from passing R5) ----------------
struct GemmArg {
  const u16* x;    // [4096][1024] bf16
  const u16* w;    // [1024][1024] bf16 (torch: y = x @ W.T + b -> NT gemm)
  const u16* bias; // [1024] bf16
  u16* dst;        // mode 3: reinterpreted as float*
  int mode;        // 0=Q (BHSD, *0.125*log2e)  1=K (BHSD)  2=V^T (BHDS)  3=fp32 [M][N]
};

__global__ __launch_bounds__(256, 2) void gemm_nt(GemmArg g0, GemmArg g1, GemmArg g2) {
  GemmArg g = (blockIdx.z == 0) ? g0 : ((blockIdx.z == 1) ? g1 : g2);
  __shared__ u16 As[128 * 32];
  __shared__ u16 Bs[128 * 32];
  const int tid = threadIdx.x, w = tid >> 6, l = tid & 63;
  const int l15 = l & 15, quad = l >> 4;
  const int bm = blockIdx.x, bn = blockIdx.y;
  const int wm = w >> 1, wn = w & 1;

  floatx4 acc[4][4];
#pragma unroll
  for (int i = 0; i < 4; ++i)
#pragma unroll
    for (int j = 0; j < 4; ++j) acc[i][j] = (floatx4){0.f, 0.f, 0.f, 0.f};

  const u16* xb = g.x + (long)(bm * 128 + w * 16 + (l >> 2)) * 1024 + (l & 3) * 8;
  const u16* wb = g.w + (long)(bn * 128 + w * 16 + (l >> 2)) * 1024 + (l & 3) * 8;
  u16* asb = &As[(w * 16) * 32];
  u16* bsb = &Bs[(w * 16) * 32];

  for (int kt = 0; kt < 32; ++kt) {
    const int k0 = kt * 32;
    __syncthreads();
#pragma unroll
    for (int p = 0; p < 2; ++p) {
      GLDS(xb + (long)p * 64 * 1024 + k0, asb + p * 64 * 32);
      GLDS(wb + (long)p * 64 * 1024 + k0, bsb + p * 64 * 32);
    }
    __syncthreads();
    short8 af[4], bfr[4];
#pragma unroll
    for (int mi = 0; mi < 4; ++mi)
      af[mi] = *(const short8*)&As[(wm * 64 + mi * 16 + l15) * 32 + quad * 8];
#pragma unroll
    for (int ni = 0; ni < 4; ++ni)
      bfr[ni] = *(const short8*)&Bs[(wn * 64 + ni * 16 + l15) * 32 + quad * 8];
#pragma unroll
    for (int mi = 0; mi < 4; ++mi)
#pragma unroll
      for (int ni = 0; ni < 4; ++ni)
        acc[mi][ni] = __builtin_amdgcn_mfma_f32_16x16x32_bf16(af[mi], bfr[ni], acc[mi][ni], 0, 0, 0);
  }

  float bv[4];
#pragma unroll
  for (int ni = 0; ni < 4; ++ni) bv[ni] = bf2f(g.bias[bn * 128 + wn * 64 + ni * 16 + l15]);

  // C/D layout: col = lane&15, row = quad*4 + reg  [m89/m91]
#pragma unroll
  for (int mi = 0; mi < 4; ++mi) {
    const int mbase = bm * 128 + wm * 64 + mi * 16 + quad * 4;
#pragma unroll
    for (int ni = 0; ni < 4; ++ni) {
      const int n = bn * 128 + wn * 64 + ni * 16 + l15;
      if (g.mode == 2) {  // V^T [B,H,64,2048]
        const int b = mbase >> 11, s = mbase & 2047;
        const int h = n >> 6, d = n & 63;
        ushortx4 u;
#pragma unroll
        for (int r = 0; r < 4; ++r) u[r] = f2bf(acc[mi][ni][r] + bv[ni]);
        *(ushortx4*)&g.dst[((long)(b * 16 + h) * 64 + d) * 2048 + s] = u;
      } else if (g.mode == 3) {  // fp32 [4096][1024] -> d_out
        float* df = (float*)g.dst;
#pragma unroll
        for (int r = 0; r < 4; ++r)
          df[(long)(mbase + r) * 1024 + n] = acc[mi][ni][r] + bv[ni];
      } else {  // Q/K -> [B,H,2048,64]; Q folds 1/sqrt(64) * log2(e) for exp2 softmax
        const float sc = (g.mode == 0) ? 0.18033688011f : 1.0f;
        const int h = n >> 6, d = n & 63;
#pragma unroll
        for (int r = 0; r < 4; ++r) {
          const int m = mbase + r, b = m >> 11, s = m & 2047;
          g.dst[((long)(b * 16 + h) * 2048 + s) * 64 + d] = f2bf((acc[mi][ni][r] + bv[ni]) * sc);
        }
      }
    }
  }
}

// ---------------- flash attention: Q-tile 128, kv-tile 64, LDS-staged K/V ----------------
// Scores arrive in log2 domain (Q pre-scaled by 0.125*log2e) -> single v_exp_f32
// per element, no clamp. P packed to bf16 via v_perm (round-half-up), 8B LDS writes.
__global__ __launch_bounds__(256, 3) void attn_flash(const u16* __restrict__ Q,
                                                     const u16* __restrict__ K,
                                                     const u16* __restrict__ V,
                                                     u16* __restrict__ X) {
  __shared__ u16 Ks[64 * 72];       // [kv][d], stride 72
  __shared__ u16 Vs[64 * 72];       // V^T [d][kv], stride 72
  __shared__ u16 Ps[4][32 * 72];    // per-wave P [q_local][kv], bf16, stride 72
  __shared__ float denW[4][32];
  const int tid = threadIdx.x, w = tid >> 6, l = tid & 63;
  const int l15 = l & 15, quad = l >> 4;
  const int q0 = blockIdx.x * 128, bh = blockIdx.y;
  const u16* qp = Q + (long)bh * 2048 * 64;  // [2048][64], pre-scaled by 0.125*log2e
  const u16* kp = K + (long)bh * 2048 * 64;  // [2048][64]
  const u16* vp = V + (long)bh * 2048 * 64;  // [64][2048] (V^T)

  // Q fragments (B-operand of S^T = K*Q^T): lane holds Q[q=l15][d=kc*32+quad*8+j]
  short8 qf[2][2];
#pragma unroll
  for (int nq = 0; nq < 2; ++nq)
#pragma unroll
    for (int kc = 0; kc < 2; ++kc)
      qf[nq][kc] = *(const short8*)(qp + (long)(q0 + w * 32 + nq * 16 + l15) * 64 + kc * 32 + quad * 8);

  floatx4 o[2][4];
#pragma unroll
  for (int mq = 0; mq < 2; ++mq)
#pragma unroll
    for (int nd = 0; nd < 4; ++nd) o[mq][nd] = (floatx4){0.f, 0.f, 0.f, 0.f};
  float den[2] = {0.f, 0.f};

  for (int kv0 = 0; kv0 < 2048; kv0 += 64) {
    __syncthreads();
    // stage K tile [64 kv][64 d] and V^T tile [64 d][64 kv]; 512 16B-chunks each
#pragma unroll
    for (int i = 0; i < 2; ++i) {
      const int ci = i * 256 + tid;
      const int r = ci >> 3, c8 = ci & 7;
      short8 tk = *(const short8*)(kp + (long)(kv0 + r) * 64 + c8 * 8);
      short8 tv = *(const short8*)(vp + (long)r * 2048 + kv0 + c8 * 8);
      *(short8*)&Ks[r * 72 + c8 * 8] = tk;
      *(short8*)&Vs[r * 72 + c8 * 8] = tv;
    }
    __syncthreads();

    // S^T[kv][q]: A = K rows (m=kv), B = Q^T (n=q). D: kv = mk*16+quad*4+r, q = l15.
#pragma unroll
    for (int mk = 0; mk < 4; ++mk) {
      short8 ak0 = *(const short8*)&Ks[(mk * 16 + l15) * 72 + quad * 8];
      short8 ak1 = *(const short8*)&Ks[(mk * 16 + l15) * 72 + 32 + quad * 8];
#pragma unroll
      for (int nq = 0; nq < 2; ++nq) {
        floatx4 st = (floatx4){0.f, 0.f, 0.f, 0.f};
        st = __builtin_amdgcn_mfma_f32_16x16x32_bf16(ak0, qf[nq][0], st, 0, 0, 0);
        st = __builtin_amdgcn_mfma_f32_16x16x32_bf16(ak1, qf[nq][1], st, 0, 0, 0);
        const float e0 = fexp2(st[0]), e1 = fexp2(st[1]);
        const float e2 = fexp2(st[2]), e3 = fexp2(st[3]);
        den[nq] += (e0 + e1) + (e2 + e3);
        uint2v pk = { pkbf(e0, e1), pkbf(e2, e3) };
        *(uint2v*)&Ps[w][(nq * 16 + l15) * 72 + mk * 16 + quad * 4] = pk;
      }
    }

    // O += P * V: A = P[m=q][k=kv] (b128 from own-wave Ps), B = V^T (n=d).
#pragma unroll
    for (int kc = 0; kc < 2; ++kc) {
#pragma unroll
      for (int mq = 0; mq < 2; ++mq) {
        short8 ap = *(const short8*)&Ps[w][(mq * 16 + l15) * 72 + kc * 32 + quad * 8];
#pragma unroll
        for (int nd = 0; nd < 4; ++nd) {
          short8 bvf = *(const short8*)&Vs[(nd * 16 + l15) * 72 + kc * 32 + quad * 8];
          o[mq][nd] = __builtin_amdgcn_mfma_f32_16x16x32_bf16(ap, bvf, o[mq][nd], 0, 0, 0);
        }
      }
    }
  }

  // denominator: lane's den[nq] covers q = nq*16+l15 for its quad's kv subset; sum quads
#pragma unroll
  for (int nq = 0; nq < 2; ++nq) {
    float d = den[nq];
    d += __shfl_xor(d, 16);
    d += __shfl_xor(d, 32);
    if (l < 16) denW[w][nq * 16 + l] = 1.0f / d;
  }

  const int b = bh >> 4, h = bh & 15;
#pragma unroll
  for (int mq = 0; mq < 2; ++mq) {
#pragma unroll
    for (int r = 0; r < 4; ++r) {
      const float rcp = denW[w][mq * 16 + quad * 4 + r];
      const int s = q0 + w * 32 + mq * 16 + quad * 4 + r;
      u16* xrow = X + ((long)(b * 2048 + s)) * 1024 + h * 64;
#pragma unroll
      for (int nd = 0; nd < 4; ++nd)
        xrow[nd * 16 + l15] = f2bf(o[mq][nd][r] * rcp);
    }
  }
}

extern "C" void kernel_launch(void* const* d_in, const int* in_sizes, int n_in,
                              void* d_out, int out_size, void* d_ws, size_t ws_size,
                              hipStream_t stream) {
  u16* ws = (u16*)d_ws;
  const size_t M1 = 1048576, M4 = 4194304;
  u16* NQ  = ws;                    // bf16 copies of fp32 inputs (NQ reused as Xb)
  u16* NK  = ws + M4;
  u16* NV  = ws + 2 * M4;
  u16* NWQ = ws + 3 * M4;
  u16* NWK = ws + 3 * M4 + M1;
  u16* NWV = ws + 3 * M4 + 2 * M1;
  u16* NWO = ws + 3 * M4 + 3 * M1;
  u16* NBQ = ws + 3 * M4 + 4 * M1;
  u16* NBK = NBQ + 1024;
  u16* NBV = NBQ + 2048;
  u16* NBO = NBQ + 3072;
  u16* Qb = ws + 16 * M1 + 8192;    // [32][2048][64], q*0.125*log2e
  u16* Kb = Qb + M4;                // [32][2048][64]
  u16* Vb = Qb + 2 * M4;            // [32][64][2048] (V^T)
  u16* Xb = NQ;                     // [4096][1024]

  CvtArg ca;
  u16* dsts[11] = {NQ, NK, NV, NWQ, NBQ, NWK, NBK, NWV, NBV, NWO, NBO};
  int sizes[11] = {(int)M4, (int)M4, (int)M4, (int)M1, 1024, (int)M1, 1024, (int)M1, 1024, (int)M1, 1024};
  int c = 0;
  for (int i = 0; i < 11; ++i) {
    ca.src[i] = (const float*)d_in[i];
    ca.dst[i] = dsts[i];
    ca.cum[i] = c;
    c += sizes[i];
  }
  ca.cum[11] = c;
  convert<<<(c / 4 + 255) / 256, 256, 0, stream>>>(ca);

  GemmArg gq{NQ, NWQ, NBQ, Qb, 0};
  GemmArg gk{NK, NWK, NBK, Kb, 1};
  GemmArg gv{NV, NWV, NBV, Vb, 2};
  gemm_nt<<<dim3(32, 8, 3), 256, 0, stream>>>(gq, gk, gv);

  attn_flash<<<dim3(16, 32), 256, 0, stream>>>(Qb, Kb, Vb, Xb);

  GemmArg go{Xb, NWO, NBO, (u16*)d_out, 3};
  gemm_nt<<<dim3(32, 8, 1), 256, 0, stream>>>(go, go, go);
}

// Round 8
// 227.832 us; speedup vs baseline: 1.7736x; 1.0549x over previous
//
#include <hip/hip_runtime.h>

typedef unsigned short u16;
typedef unsigned int u32;
typedef __attribute__((ext_vector_type(8))) short short8;
typedef __attribute__((ext_vector_type(4))) float floatx4;
typedef __attribute__((ext_vector_type(4))) unsigned short ushortx4;
typedef __attribute__((ext_vector_type(2))) unsigned int uint2v;

#define DEV static __device__ __forceinline__

DEV float bf2f(u16 u) { union { unsigned u; float f; } v; v.u = ((unsigned)u) << 16; return v.f; }
DEV u16 f2bf(float f) {
  union { float f; unsigned u; } v; v.f = f;
  return (u16)((v.u + 0x7FFFu + ((v.u >> 16) & 1u)) >> 16);  // RNE; finite inputs
}
// pack two floats to two bf16 (round-half-up) in one v_perm
DEV u32 pkbf(float a, float b) {
  union { float f; u32 u; } x, y; x.f = a; y.f = b;
  return __builtin_amdgcn_perm(y.u + 0x8000u, x.u + 0x8000u, 0x07060302u);
}
DEV float fexp2(float x) { return __builtin_amdgcn_exp2f(x); }  // v_exp_f32

// async global->LDS, 16B/lane, LDS dest = wave-uniform base + lane*16 (m97-proven form)
#define GLDS(g, l) __builtin_amdgcn_global_load_lds( \
    (const __attribute__((address_space(1))) void*)(g), \
    (__attribute__((address_space(3))) void*)(l), 16, 0, 0)

// ---------------- fp32 -> bf16 conversion of all 11 inputs ----------------
struct CvtArg {
  const float* src[11];
  u16* dst[11];
  int cum[12];
};

__global__ void convert(CvtArg a) {
  const long base = ((long)blockIdx.x * 256 + threadIdx.x) * 4;
  if (base >= a.cum[11]) return;
  int s = 0;
  while (s < 10 && base >= a.cum[s + 1]) ++s;
  const long off = base - a.cum[s];
  const float* sp = a.src[s] + off;
  ushortx4 u;
#pragma unroll
  for (int r = 0; r < 4; ++r) u[r] = f2bf(sp[r]);
  *(ushortx4*)(a.dst[s] + off) = u;
}

// ---------------- projection GEMMs (m97 structure; verbatim from passing R7) ----------------
struct GemmArg {
  const u16* x;    // [4096][1024] bf16
  const u16* w;    // [1024][1024] bf16 (torch: y = x @ W.T + b -> NT gemm)
  const u16* bias; // [1024] bf16
  u16* dst;        // mode 3: reinterpreted as float*
  int mode;        // 0=Q (BHSD, *0.125*log2e)  1=K (BHSD)  2=V^T (BHDS)  3=fp32 [M][N]
};

__global__ __launch_bounds__(256, 2) void gemm_nt(GemmArg g0, GemmArg g1, GemmArg g2) {
  GemmArg g = (blockIdx.z == 0) ? g0 : ((blockIdx.z == 1) ? g1 : g2);
  __shared__ u16 As[128 * 32];
  __shared__ u16 Bs[128 * 32];
  const int tid = threadIdx.x, w = tid >> 6, l = tid & 63;
  const int l15 = l & 15, quad = l >> 4;
  const int bm = blockIdx.x, bn = blockIdx.y;
  const int wm = w >> 1, wn = w & 1;

  floatx4 acc[4][4];
#pragma unroll
  for (int i = 0; i < 4; ++i)
#pragma unroll
    for (int j = 0; j < 4; ++j) acc[i][j] = (floatx4){0.f, 0.f, 0.f, 0.f};

  const u16* xb = g.x + (long)(bm * 128 + w * 16 + (l >> 2)) * 1024 + (l & 3) * 8;
  const u16* wb = g.w + (long)(bn * 128 + w * 16 + (l >> 2)) * 1024 + (l & 3) * 8;
  u16* asb = &As[(w * 16) * 32];
  u16* bsb = &Bs[(w * 16) * 32];

  for (int kt = 0; kt < 32; ++kt) {
    const int k0 = kt * 32;
    __syncthreads();
#pragma unroll
    for (int p = 0; p < 2; ++p) {
      GLDS(xb + (long)p * 64 * 1024 + k0, asb + p * 64 * 32);
      GLDS(wb + (long)p * 64 * 1024 + k0, bsb + p * 64 * 32);
    }
    __syncthreads();
    short8 af[4], bfr[4];
#pragma unroll
    for (int mi = 0; mi < 4; ++mi)
      af[mi] = *(const short8*)&As[(wm * 64 + mi * 16 + l15) * 32 + quad * 8];
#pragma unroll
    for (int ni = 0; ni < 4; ++ni)
      bfr[ni] = *(const short8*)&Bs[(wn * 64 + ni * 16 + l15) * 32 + quad * 8];
#pragma unroll
    for (int mi = 0; mi < 4; ++mi)
#pragma unroll
      for (int ni = 0; ni < 4; ++ni)
        acc[mi][ni] = __builtin_amdgcn_mfma_f32_16x16x32_bf16(af[mi], bfr[ni], acc[mi][ni], 0, 0, 0);
  }

  float bv[4];
#pragma unroll
  for (int ni = 0; ni < 4; ++ni) bv[ni] = bf2f(g.bias[bn * 128 + wn * 64 + ni * 16 + l15]);

  // C/D layout: col = lane&15, row = quad*4 + reg  [m89/m91]
#pragma unroll
  for (int mi = 0; mi < 4; ++mi) {
    const int mbase = bm * 128 + wm * 64 + mi * 16 + quad * 4;
#pragma unroll
    for (int ni = 0; ni < 4; ++ni) {
      const int n = bn * 128 + wn * 64 + ni * 16 + l15;
      if (g.mode == 2) {  // V^T [B,H,64,2048]
        const int b = mbase >> 11, s = mbase & 2047;
        const int h = n >> 6, d = n & 63;
        ushortx4 u;
#pragma unroll
        for (int r = 0; r < 4; ++r) u[r] = f2bf(acc[mi][ni][r] + bv[ni]);
        *(ushortx4*)&g.dst[((long)(b * 16 + h) * 64 + d) * 2048 + s] = u;
      } else if (g.mode == 3) {  // fp32 [4096][1024] -> d_out
        float* df = (float*)g.dst;
#pragma unroll
        for (int r = 0; r < 4; ++r)
          df[(long)(mbase + r) * 1024 + n] = acc[mi][ni][r] + bv[ni];
      } else {  // Q/K -> [B,H,2048,64]; Q folds 1/sqrt(64) * log2(e) for exp2 softmax
        const float sc = (g.mode == 0) ? 0.18033688011f : 1.0f;
        const int h = n >> 6, d = n & 63;
#pragma unroll
        for (int r = 0; r < 4; ++r) {
          const int m = mbase + r, b = m >> 11, s = m & 2047;
          g.dst[((long)(b * 16 + h) * 2048 + s) * 64 + d] = f2bf((acc[mi][ni][r] + bv[ni]) * sc);
        }
      }
    }
  }
}

// ---------------- flash attention: double-buffered K/V staging ----------------
// Loads for tile t+1 issued before compute of tile t; stored to the idle buffer
// after compute; ONE barrier per iteration. Ps is per-wave (no barrier needed).
__global__ __launch_bounds__(256, 2) void attn_flash(const u16* __restrict__ Q,
                                                     const u16* __restrict__ K,
                                                     const u16* __restrict__ V,
                                                     u16* __restrict__ X) {
  __shared__ u16 Ks[2][64 * 72];    // [kv][d], stride 72
  __shared__ u16 Vs[2][64 * 72];    // V^T [d][kv], stride 72
  __shared__ u16 Ps[4][32 * 72];    // per-wave P [q_local][kv], bf16, stride 72
  __shared__ float denW[4][32];
  const int tid = threadIdx.x, w = tid >> 6, l = tid & 63;
  const int l15 = l & 15, quad = l >> 4;
  const int q0 = blockIdx.x * 128, bh = blockIdx.y;
  const u16* qp = Q + (long)bh * 2048 * 64;  // [2048][64], pre-scaled by 0.125*log2e
  const u16* kp = K + (long)bh * 2048 * 64;  // [2048][64]
  const u16* vp = V + (long)bh * 2048 * 64;  // [64][2048] (V^T)

  // staging map: thread covers 16B chunks ci0=tid, ci1=256+tid of the 512-chunk tile pair
  const int r0 = tid >> 3, c0 = tid & 7;            // rows 0..31
  const int r1 = (256 + tid) >> 3, c1 = tid & 7;    // rows 32..63

#define ISSUE_LOADS(kv0) \
    sk0 = *(const short8*)(kp + (long)((kv0) + r0) * 64 + c0 * 8); \
    sv0 = *(const short8*)(vp + (long)r0 * 2048 + (kv0) + c0 * 8); \
    sk1 = *(const short8*)(kp + (long)((kv0) + r1) * 64 + c1 * 8); \
    sv1 = *(const short8*)(vp + (long)r1 * 2048 + (kv0) + c1 * 8);

#define STORE_TILE(pb) \
    *(short8*)&Ks[pb][r0 * 72 + c0 * 8] = sk0; \
    *(short8*)&Vs[pb][r0 * 72 + c0 * 8] = sv0; \
    *(short8*)&Ks[pb][r1 * 72 + c1 * 8] = sk1; \
    *(short8*)&Vs[pb][r1 * 72 + c1 * 8] = sv1;

  short8 sk0, sv0, sk1, sv1;

  // Q fragments (B-operand of S^T = K*Q^T): lane holds Q[q=l15][d=kc*32+quad*8+j]
  short8 qf[2][2];
#pragma unroll
  for (int nq = 0; nq < 2; ++nq)
#pragma unroll
    for (int kc = 0; kc < 2; ++kc)
      qf[nq][kc] = *(const short8*)(qp + (long)(q0 + w * 32 + nq * 16 + l15) * 64 + kc * 32 + quad * 8);

  floatx4 o[2][4];
#pragma unroll
  for (int mq = 0; mq < 2; ++mq)
#pragma unroll
    for (int nd = 0; nd < 4; ++nd) o[mq][nd] = (floatx4){0.f, 0.f, 0.f, 0.f};
  float den[2] = {0.f, 0.f};

  // prologue: tile 0 -> buf0; tile 1 in flight
  ISSUE_LOADS(0)
  STORE_TILE(0)
  ISSUE_LOADS(64)
  __syncthreads();

  for (int t = 0; t < 32; ++t) {
    const int p = t & 1;

    // S^T[kv][q]: A = K rows (m=kv), B = Q^T (n=q). D: kv = mk*16+quad*4+r, q = l15.
#pragma unroll
    for (int mk = 0; mk < 4; ++mk) {
      short8 ak0 = *(const short8*)&Ks[p][(mk * 16 + l15) * 72 + quad * 8];
      short8 ak1 = *(const short8*)&Ks[p][(mk * 16 + l15) * 72 + 32 + quad * 8];
#pragma unroll
      for (int nq = 0; nq < 2; ++nq) {
        floatx4 st = (floatx4){0.f, 0.f, 0.f, 0.f};
        st = __builtin_amdgcn_mfma_f32_16x16x32_bf16(ak0, qf[nq][0], st, 0, 0, 0);
        st = __builtin_amdgcn_mfma_f32_16x16x32_bf16(ak1, qf[nq][1], st, 0, 0, 0);
        const float e0 = fexp2(st[0]), e1 = fexp2(st[1]);
        const float e2 = fexp2(st[2]), e3 = fexp2(st[3]);
        den[nq] += (e0 + e1) + (e2 + e3);
        uint2v pk = { pkbf(e0, e1), pkbf(e2, e3) };
        *(uint2v*)&Ps[w][(nq * 16 + l15) * 72 + mk * 16 + quad * 4] = pk;
      }
    }

    // O += P * V: ap/bvf hoisted — 12 ds_read_b128 per iter
#pragma unroll
    for (int kc = 0; kc < 2; ++kc) {
      short8 ap0 = *(const short8*)&Ps[w][l15 * 72 + kc * 32 + quad * 8];
      short8 ap1 = *(const short8*)&Ps[w][(16 + l15) * 72 + kc * 32 + quad * 8];
#pragma unroll
      for (int nd = 0; nd < 4; ++nd) {
        short8 bvf = *(const short8*)&Vs[p][(nd * 16 + l15) * 72 + kc * 32 + quad * 8];
        o[0][nd] = __builtin_amdgcn_mfma_f32_16x16x32_bf16(ap0, bvf, o[0][nd], 0, 0, 0);
        o[1][nd] = __builtin_amdgcn_mfma_f32_16x16x32_bf16(ap1, bvf, o[1][nd], 0, 0, 0);
      }
    }

    // stage tile t+1 into the idle buffer; issue loads for t+2
    if (t < 31) {
      STORE_TILE(p ^ 1)
      if (t < 30) {
        const int nxt = (t + 2) * 64;
        ISSUE_LOADS(nxt)
      }
    }
    __syncthreads();
  }

  // denominator: lane's den[nq] covers q = nq*16+l15 for its quad's kv subset; sum quads
#pragma unroll
  for (int nq = 0; nq < 2; ++nq) {
    float d = den[nq];
    d += __shfl_xor(d, 16);
    d += __shfl_xor(d, 32);
    if (l < 16) denW[w][nq * 16 + l] = 1.0f / d;
  }

  const int b = bh >> 4, h = bh & 15;
#pragma unroll
  for (int mq = 0; mq < 2; ++mq) {
#pragma unroll
    for (int r = 0; r < 4; ++r) {
      const float rcp = denW[w][mq * 16 + quad * 4 + r];
      const int s = q0 + w * 32 + mq * 16 + quad * 4 + r;
      u16* xrow = X + ((long)(b * 2048 + s)) * 1024 + h * 64;
#pragma unroll
      for (int nd = 0; nd < 4; ++nd)
        xrow[nd * 16 + l15] = f2bf(o[mq][nd][r] * rcp);
    }
  }
}

extern "C" void kernel_launch(void* const* d_in, const int* in_sizes, int n_in,
                              void* d_out, int out_size, void* d_ws, size_t ws_size,
                              hipStream_t stream) {
  u16* ws = (u16*)d_ws;
  const size_t M1 = 1048576, M4 = 4194304;
  u16* NQ  = ws;                    // bf16 copies of fp32 inputs (NQ reused as Xb)
  u16* NK  = ws + M4;
  u16* NV  = ws + 2 * M4;
  u16* NWQ = ws + 3 * M4;
  u16* NWK = ws + 3 * M4 + M1;
  u16* NWV = ws + 3 * M4 + 2 * M1;
  u16* NWO = ws + 3 * M4 + 3 * M1;
  u16* NBQ = ws + 3 * M4 + 4 * M1;
  u16* NBK = NBQ + 1024;
  u16* NBV = NBQ + 2048;
  u16* NBO = NBQ + 3072;
  u16* Qb = ws + 16 * M1 + 8192;    // [32][2048][64], q*0.125*log2e
  u16* Kb = Qb + M4;                // [32][2048][64]
  u16* Vb = Qb + 2 * M4;            // [32][64][2048] (V^T)
  u16* Xb = NQ;                     // [4096][1024]

  CvtArg ca;
  u16* dsts[11] = {NQ, NK, NV, NWQ, NBQ, NWK, NBK, NWV, NBV, NWO, NBO};
  int sizes[11] = {(int)M4, (int)M4, (int)M4, (int)M1, 1024, (int)M1, 1024, (int)M1, 1024, (int)M1, 1024};
  int c = 0;
  for (int i = 0; i < 11; ++i) {
    ca.src[i] = (const float*)d_in[i];
    ca.dst[i] = dsts[i];
    ca.cum[i] = c;
    c += sizes[i];
  }
  ca.cum[11] = c;
  convert<<<(c / 4 + 255) / 256, 256, 0, stream>>>(ca);

  GemmArg gq{NQ, NWQ, NBQ, Qb, 0};
  GemmArg gk{NK, NWK, NBK, Kb, 1};
  GemmArg gv{NV, NWV, NBV, Vb, 2};
  gemm_nt<<<dim3(32, 8, 3), 256, 0, stream>>>(gq, gk, gv);

  attn_flash<<<dim3(16, 32), 256, 0, stream>>>(Qb, Kb, Vb, Xb);

  GemmArg go{Xb, NWO, NBO, (u16*)d_out, 3};
  gemm_nt<<<dim3(32, 8, 1), 256, 0, stream>>>(go, go, go);
}